// Round 3
// baseline (186.421 us; speedup 1.0000x reference)
//
#include <hip/hip_runtime.h>

#define ALPHA 0.2f
#define NEG_INF -9e15f

__device__ __forceinline__ float dot4(float4 a, float4 b) {
    return a.x * b.x + a.y * b.y + a.z * b.z + a.w * b.w;
}

__device__ __forceinline__ void wave_lds_fence() {
    // intra-wave LDS visibility: drain DS ops; no block barrier needed
    asm volatile("s_waitcnt lgkmcnt(0)" ::: "memory");
    __builtin_amdgcn_sched_barrier(0);
}

// K1: one wave per node. attention + aggregation + residual -> y (= d_out)
__global__ __launch_bounds__(256, 3)
void gat_k1(const float* __restrict__ item,
            const float* __restrict__ ent,
            const float* __restrict__ rel,
            const int*   __restrict__ rel_ids,
            const int*   __restrict__ adj,
            const float* __restrict__ fc_w,
            const float* __restrict__ fc_b,
            const float* __restrict__ probs,
            float* __restrict__ y,
            int N, int R)
{
    __shared__ float e_lds[4][32];   // per-wave strips, 512 B total

    const int t  = threadIdx.x;
    const int wv = t >> 6;           // wave in block
    const int l  = t & 63;           // lane
    const int lh = l & 31;           // lane-in-half
    const int hi = l >> 5;           // half index (k parity)

    const int n = blockIdx.x * 4 + wv;
    if (n >= N) return;

    // fc_w fragments for this lane's dims d = 4*lh + i
    const float4 fi = *(const float4*)&fc_w[4 * lh];          // item coeffs
    const float4 fr = *(const float4*)&fc_w[128 + 4 * lh];    // relation coeffs
    const float4 fe = *(const float4*)&fc_w[256 + 4 * lh];    // entity coeffs
    const float  fcb = fc_b[0];

    const size_t nb = (size_t)n * 4096;
    const float4 item4 = *(const float4*)&item[(size_t)n * 128 + 4 * lh];
    const int    adjv  = adj[(size_t)n * 32 + lh];
    const int    idv   = rel_ids[(size_t)n * 32 + lh];

    // relation-domain prob row-sum for this lane's k = lh (issued early)
    const bool  valid = (idv >= 0) && (idv < R);
    const int   sid   = valid ? idv : 0;
    const float4 q    = *(const float4*)&probs[sid * 4];

    // ---- load rel/ent (coalesced 1KB/inst), products + e-partials --------
    float4 p[16];     // rel*ent for k=2c+hi, dims 4lh..+3
    float  ep[16];    // e-contribution of this lane for k=2c+hi
    #pragma unroll
    for (int h = 0; h < 2; ++h) {
        float4 rv[8], ev[8];
        #pragma unroll
        for (int c = 0; c < 8; ++c)
            rv[c] = *(const float4*)&rel[nb + (h * 8 + c) * 256 + l * 4];
        #pragma unroll
        for (int c = 0; c < 8; ++c)
            ev[c] = *(const float4*)&ent[nb + (h * 8 + c) * 256 + l * 4];
        #pragma unroll
        for (int c = 0; c < 8; ++c) {
            const int cc = h * 8 + c;
            float4 pp;
            pp.x = rv[c].x * ev[c].x;
            pp.y = rv[c].y * ev[c].y;
            pp.z = rv[c].z * ev[c].z;
            pp.w = rv[c].w * ev[c].w;
            p[cc]  = pp;
            ep[cc] = dot4(rv[c], fr) + dot4(ev[c], fe);
        }
    }

    // item dot (identical in both halves; reduce width 32)
    float sit = dot4(item4, fi);
    #pragma unroll
    for (int s = 16; s >= 1; s >>= 1) sit += __shfl_xor(sit, s, 32);

    // reduce each chunk's e over its 32-lane half -> every lane holds e[2c+hi]
    #pragma unroll
    for (int c = 0; c < 16; ++c) {
        float v = ep[c];
        #pragma unroll
        for (int s = 16; s >= 1; s >>= 1) v += __shfl_xor(v, s, 32);
        ep[c] = v;
    }
    if (lh == 0) {
        #pragma unroll
        for (int c = 0; c < 16; ++c) e_lds[wv][2 * c + hi] = ep[c];
    }
    wave_lds_fence();

    // ---- masked softmax, lane-parallel over k = lh -----------------------
    float em = e_lds[wv][lh] + sit + fcb;
    em = (em > 0.0f) ? em : ALPHA * em;                 // LeakyReLU
    float m = (adjv > 0) ? em : NEG_INF;                // adjacency mask
    float mx = m;
    #pragma unroll
    for (int s = 16; s >= 1; s >>= 1) mx = fmaxf(mx, __shfl_xor(mx, s, 32));
    float pe = __expf(m - mx);
    float ps = pe;
    #pragma unroll
    for (int s = 16; s >= 1; s >>= 1) ps += __shfl_xor(ps, s, 32);
    const float a  = valid ? (q.x + q.y + q.z + q.w) : 0.0f;
    const float wk = (pe / ps) * a;                     // weight for k = lh

    // ---- aggregate: acc += w[2c+hi] * p[c], merge halves -----------------
    float4 acc = make_float4(0.f, 0.f, 0.f, 0.f);
    #pragma unroll
    for (int c = 0; c < 16; ++c) {
        const float wc = __shfl(wk, 2 * c + hi, 64);    // w held by lane k
        acc.x = fmaf(wc, p[c].x, acc.x);
        acc.y = fmaf(wc, p[c].y, acc.y);
        acc.z = fmaf(wc, p[c].z, acc.z);
        acc.w = fmaf(wc, p[c].w, acc.w);
    }
    acc.x += __shfl_xor(acc.x, 32, 64);
    acc.y += __shfl_xor(acc.y, 32, 64);
    acc.z += __shfl_xor(acc.z, 32, 64);
    acc.w += __shfl_xor(acc.w, 32, 64);

    if (l < 32) {
        float4 o;
        o.x = acc.x + item4.x;
        o.y = acc.y + item4.y;
        o.z = acc.z + item4.z;
        o.w = acc.w + item4.w;
        *(float4*)&y[(size_t)n * 128 + 4 * lh] = o;
    }
}

// K2: out = relu(y @ W^T + b), in place on d_out.
__device__ __forceinline__ void block_bar() {
    asm volatile("s_waitcnt lgkmcnt(0)" ::: "memory");
    __builtin_amdgcn_s_barrier();
}

__global__ __launch_bounds__(256, 4)
void gat_k2(const float* __restrict__ out_w,
            const float* __restrict__ out_b,
            float* __restrict__ y, int N)
{
    __shared__ __align__(16) float ylds[128];
    __shared__ __align__(16) float plds[1024];   // [4 a][32 g][8 c]

    const int t = threadIdx.x;
    const int c = t & 7;
    const int g = t >> 3;

    float4 w4[16];   // W[4g+a][c*16 ...] stays register-resident
    #pragma unroll
    for (int a = 0; a < 4; ++a)
        #pragma unroll
        for (int i = 0; i < 4; ++i)
            w4[a * 4 + i] = *(const float4*)&out_w[(size_t)(g * 4 + a) * 128 + c * 16 + i * 4];
    const float bj = out_b[t & 127];
    const int stride = gridDim.x;

    float vcur = 0.0f;
    if (t < 128) vcur = y[(size_t)blockIdx.x * 128 + t];

    for (int n = blockIdx.x; n < N; n += stride) {
        if (t < 128) ylds[t] = vcur;
        block_bar();
        int np = n + stride; if (np >= N) np = n;
        float vn = 0.0f;
        if (t < 128) vn = y[(size_t)np * 128 + t];

        float4 yc[4];
        #pragma unroll
        for (int i = 0; i < 4; ++i) yc[i] = *(const float4*)&ylds[c * 16 + i * 4];
        #pragma unroll
        for (int a = 0; a < 4; ++a) {
            float s = 0.0f;
            #pragma unroll
            for (int i = 0; i < 4; ++i) s += dot4(w4[a * 4 + i], yc[i]);
            plds[a * 256 + g * 8 + c] = s;
        }
        block_bar();
        if (t < 128) {
            const int j = t, a2 = j & 3, g2 = j >> 2;
            const float* pp = &plds[a2 * 256 + g2 * 8];
            float4 u0 = *(const float4*)pp;
            float4 u1 = *(const float4*)(pp + 4);
            float s = u0.x + u0.y + u0.z + u0.w + u1.x + u1.y + u1.z + u1.w + bj;
            y[(size_t)n * 128 + j] = fmaxf(s, 0.0f);
        }
        vcur = vn;
    }
}

extern "C" void kernel_launch(void* const* d_in, const int* in_sizes, int n_in,
                              void* d_out, int out_size, void* d_ws, size_t ws_size,
                              hipStream_t stream) {
    const float* item    = (const float*)d_in[0];
    const float* ent     = (const float*)d_in[1];
    const float* rel     = (const float*)d_in[2];
    const int*   rel_ids = (const int*)  d_in[3];
    const int*   adj     = (const int*)  d_in[4];
    const float* fc_w    = (const float*)d_in[5];
    const float* fc_b    = (const float*)d_in[6];
    const float* out_w   = (const float*)d_in[7];
    const float* out_b   = (const float*)d_in[8];
    const float* probs   = (const float*)d_in[9];
    float* out = (float*)d_out;

    const int N = in_sizes[0] / 128;   // 20000
    const int R = in_sizes[9] / 4;     // 100

    const int blocks1 = (N + 3) / 4;   // one wave per node
    hipLaunchKernelGGL(gat_k1, dim3(blocks1), dim3(256), 0, stream,
                       item, ent, rel, rel_ids, adj, fc_w, fc_b, probs, out, N, R);

    int blocks2 = 2048; if (blocks2 > N) blocks2 = N;
    hipLaunchKernelGGL(gat_k2, dim3(blocks2), dim3(256), 0, stream,
                       out_w, out_b, out, N);
}